// Round 8
// baseline (429.755 us; speedup 1.0000x reference)
//
#include <hip/hip_runtime.h>
#include <math.h>

// FourierConv via DFT-as-GEMM on the MATRIX pipe.
// out[b,h,w,c] = Re(ifft2(fft2(x,255^2)*Ksum))[h+63,w+63] + bias; Ksum = sum_cout K.
// Half-spectrum q=0..127. Stages 1 (n->q), 2 (m->p), 4 (p->h), 5 (q->w real part) are
// bf16 MFMA GEMMs with SPLIT precision (rel err ~2^-17).
// Operand-fragment rule (verified): both MFMA operands use layout [entity=lane&15][k=quad*8+j];
// first arg's entity -> D row (quad*4+reg), second arg's entity -> D col (lane&15).
// stage4 computes D[q][h] (A=Z, B=T4) so its epilogue emits V directly in stage5's
// A-operand bf16 layout (a5); stage1g likewise emits U directly in stage2's B-operand
// layout (ub). stage5 is a K=256 GEMM + epilogue.
//
// R6 lesson: hipLaunchCooperativeKernel silently no-ops under the harness's graph capture
// (absmax == max|ref| -> backend never ran). R7: same phase fusion, NORMAL launch of 512
// blocks (co-resident: __launch_bounds__(256,2) -> 2 blocks/CU x 256 CU, no LDS) with a
// manual sense-reversing grid barrier on __hip_atomic_* AGENT-scope (acq/rel emits the
// cross-XCD L2 wb/inv per the gfx950 memory model; Guideline 16). Barrier words in
// workspace, zeroed each launch via hipMemsetAsync (capture-safe). Phase bodies are
// byte-identical to the verified R5 kernels.

constexpr float PI2_OVER_N = 6.28318530717958647692f / 255.0f;
constexpr float INV_N2 = 1.0f / (255.0f * 255.0f);
constexpr unsigned NBLK = 512;

typedef __attribute__((ext_vector_type(8))) short bf16x8;   // 8 bf16 = 4 VGPR
typedef __attribute__((ext_vector_type(4))) float f32x4;    // MFMA acc / native float4
#define MFMA16 __builtin_amdgcn_mfma_f32_16x16x32_bf16

__device__ __forceinline__ int remap_bc(int xidx) {
  int k = xidx & 7, j = xidx >> 3;
  return ((k >> 1) * 16) + ((k & 1) * 8) + j;   // b = k>>1, c = (k&1)*8 + j
}

__device__ __forceinline__ unsigned short bf16h(float f) {
  unsigned u = __float_as_uint(f);
  return (unsigned short)((u + 0x7FFFu + ((u >> 16) & 1u)) >> 16);
}
__device__ __forceinline__ float bf16f(unsigned short h) {
  return __uint_as_float(((unsigned)h) << 16);
}

// Sense-reversing grid barrier; all NBLK blocks must be co-resident.
__device__ __forceinline__ void grid_barrier(unsigned* bar, unsigned* gen) {
  __syncthreads();
  if (threadIdx.x == 0) {
    unsigned g = __hip_atomic_load(gen, __ATOMIC_RELAXED, __HIP_MEMORY_SCOPE_AGENT);
    unsigned a = __hip_atomic_fetch_add(bar, 1u, __ATOMIC_ACQ_REL, __HIP_MEMORY_SCOPE_AGENT);
    if (a == NBLK - 1) {
      __hip_atomic_store(bar, 0u, __ATOMIC_RELAXED, __HIP_MEMORY_SCOPE_AGENT);
      __hip_atomic_store(gen, g + 1u, __ATOMIC_RELEASE, __HIP_MEMORY_SCOPE_AGENT);
    } else {
      while (__hip_atomic_load(gen, __ATOMIC_ACQUIRE, __HIP_MEMORY_SCOPE_AGENT) == g) {
        __builtin_amdgcn_s_sleep(8);
      }
    }
  }
  __syncthreads();
}

// ---------- front bodies ----------

__device__ __forceinline__ void ksum_body(
    int buf, int xb, const float* __restrict__ kr, const float* __restrict__ ki,
    float* __restrict__ Sr, float* __restrict__ Si) {
  const int nrows = 255 * 255 * 16;
  int r = xb * 256 + threadIdx.x;
  if (r >= nrows) return;
  const float* src = (buf == 0) ? kr : ki;
  float* dst = (buf == 0) ? Sr : Si;
  const float4* k4 = (const float4*)(src + (size_t)r * 16);
  float4 a = k4[0], b = k4[1], c = k4[2], d = k4[3];
  dst[r] = a.x + a.y + a.z + a.w + b.x + b.y + b.z + b.w +
           c.x + c.y + c.z + c.w + d.x + d.y + d.z + d.w;
}

// pack_x: xp[bc][plane2: H,L][((mt*16+noct)*16+mcol)*8+j] = split(x[b, m, n, c]),
// m = mt*16+mcol, n = noct*8+j. This is stage1g's A-operand layout (entity=m, k=n).
__device__ __forceinline__ void packx_body(
    int pid, const float* __restrict__ x, short* __restrict__ xp) {
  int bc = pid & 63;                         // b*16 + c
  int mt = pid >> 6;                         // 0..7
  int b = bc >> 4, c = bc & 15;
  int mcol = threadIdx.x & 15;
  int noct = threadIdx.x >> 4;               // 0..15
  int m = mt * 16 + mcol;
  const float* xs = x + ((size_t)(b * 128 + m) * 128 + noct * 8) * 16 + c;
  unsigned short hi[8], lo[8];
#pragma unroll
  for (int j = 0; j < 8; ++j) {
    float v = xs[j * 16];
    hi[j] = bf16h(v);
    lo[j] = bf16h(v - bf16f(hi[j]));
  }
  size_t base = (size_t)bc * 32768 + ((size_t)(mt * 16 + noct) * 16 + mcol) * 8;
  uint4 o;
  o.x = (unsigned)hi[0] | ((unsigned)hi[1] << 16);
  o.y = (unsigned)hi[2] | ((unsigned)hi[3] << 16);
  o.z = (unsigned)hi[4] | ((unsigned)hi[5] << 16);
  o.w = (unsigned)hi[6] | ((unsigned)hi[7] << 16);
  *(uint4*)(xp + base) = o;
  o.x = (unsigned)lo[0] | ((unsigned)lo[1] << 16);
  o.y = (unsigned)lo[2] | ((unsigned)lo[3] << 16);
  o.z = (unsigned)lo[4] | ((unsigned)lo[5] << 16);
  o.w = (unsigned)lo[6] | ((unsigned)lo[7] << 16);
  *(uint4*)(xp + base + 16384) = o;
}

// t1[plane4: cosH,cosL,(-sin)H,(-sin)L][qt8][noct16][qcol16][j8]: E[q][n] = e^{-i th q n}
__device__ __forceinline__ void buildt1_body(int cid, short* __restrict__ t1) {
  int i = cid * 256 + threadIdx.x;           // < 65536
  int plane = i >> 14;
  int r = i & 16383;
  int qt = r >> 11, noct = (r >> 7) & 15, qcol = (r >> 3) & 15, j = r & 7;
  int q = qt * 16 + qcol, n = noct * 8 + j;
  float s, c;
  sincosf(PI2_OVER_N * (float)((q * n) % 255), &s, &c);
  float src = (plane < 2) ? c : -s;
  unsigned short hh = bf16h(src);
  t1[i] = (short)((plane & 1) ? bf16h(src - bf16f(hh)) : hh);
}

// t2[plane6][pt16][moct16][p16][j8]: T2[p][m]=e^{-i th p m}; planes cosH,cosL,TiH,TiL,-TiH,-TiL
// t4[plane6][ht8][poct32][h16][j8]:  T4[h][p]=e^{+i th (h+63)p}; p=255 slot zeroed (K-pad)
// t5[plane4][wt8][koct32][w16][j8]:  T5[w][k]: q=k&127; planes cosH,cosL,(-sin)H,(-sin)L
__device__ __forceinline__ void buildt24_body(
    int cid2, short* __restrict__ t2, short* __restrict__ t4, short* __restrict__ t5) {
  int i = cid2 * 256 + threadIdx.x;          // < 524288
  float s, c;
  if (i < 196608) {
    int plane = i >> 15;
    int r = i & 32767;
    int pt = r >> 11, r2 = r & 2047;
    int moct = r2 >> 7, p = (r2 >> 3) & 15, j = r2 & 7;
    int pg = pt * 16 + p, m = moct * 8 + j;
    int k = ((pg % 255) * m) % 255;
    sincosf(PI2_OVER_N * (float)k, &s, &c);
    float ti = -s;
    float src = (plane < 2) ? c : ((plane < 4) ? ti : -ti);
    unsigned short h = bf16h(src);
    t2[i] = (short)((plane & 1) ? bf16h(src - bf16f(h)) : h);
  } else if (i < 393216) {
    int i2 = i - 196608;
    int plane = i2 >> 15;
    int r = i2 & 32767;
    int ht = r >> 12, r2 = r & 4095;
    int poct = r2 >> 7, h = (r2 >> 3) & 15, j = r2 & 7;
    int p = poct * 8 + j;
    unsigned short val = 0;
    if (p < 255) {
      int hg = ht * 16 + h;
      int k = ((hg + 63) * p) % 255;
      sincosf(PI2_OVER_N * (float)k, &s, &c);
      float src = (plane < 2) ? c : ((plane < 4) ? s : -s);
      unsigned short hh = bf16h(src);
      val = (plane & 1) ? bf16h(src - bf16f(hh)) : hh;
    }
    t4[i2] = (short)val;
  } else {
    int i3 = i - 393216;
    int plane = i3 >> 15;                    // 0..3
    int r = i3 & 32767;
    int wt = r >> 12, r2 = r & 4095;
    int ko = r2 >> 7, wl = (r2 >> 3) & 15, j = r2 & 7;
    int q = (ko * 8 + j) & 127;              // k -> q (both segs identical)
    int ww = wt * 16 + wl;
    sincosf(PI2_OVER_N * (float)(((ww + 63) * q) % 255), &s, &c);
    float src = (plane < 2) ? c : -s;
    unsigned short hh = bf16h(src);
    t5[i3] = (short)((plane & 1) ? bf16h(src - bf16f(hh)) : hh);
  }
}

// fused front: stripe of 4 -> 3 ksum blocks : 1 compute block (pack_x / t1 / t24)
__global__ __launch_bounds__(256) void fused_front(
    const float* __restrict__ kr, const float* __restrict__ ki,
    float* __restrict__ Sr, float* __restrict__ Si,
    const float* __restrict__ x, short* __restrict__ xp,
    short* __restrict__ t1, short* __restrict__ t2,
    short* __restrict__ t4, short* __restrict__ t5) {
  int bid = blockIdx.x;                      // 0..11263
  int d = bid >> 2, r = bid & 3;             // d 0..2815
  if (r == 3) {
    if (d < 512)      packx_body(d, x, xp);
    else if (d < 768) buildt1_body(d - 512, t1);
    else              buildt24_body(d - 768, t2, t4, t5);
  } else {
    int kid = d * 3 + r;
    if (kid < 8192) ksum_body(kid & 1, kid >> 1, kr, ki, Sr, Si);
  }
}

// ---------- back-end phase bodies ----------

__device__ __forceinline__ void fold_body(
    int fid, const float* __restrict__ Sr, const float* __restrict__ Si,
    float2* __restrict__ keff2) {
  int p = fid % 255;
  int qy = fid / 255;                        // 0..7
  int q = qy * 16 + (threadIdx.x >> 4);
  int c = threadIdx.x & 15;
  int pp = (255 - p) % 255;
  int qq = (255 - q) % 255;
  size_t i0 = (size_t)(p * 255 + q) * 16 + c;
  size_t i1 = (size_t)(pp * 255 + qq) * 16 + c;
  float sr0 = Sr[i0], si0 = Si[i0], sr1 = Sr[i1], si1 = Si[i1];
  float2 v;
  v.x = 0.5f * (sr0 + sr1);
  v.y = 0.5f * (si0 - si1);
  keff2[((size_t)c * 255 + p) * 128 + q] = v;
}

// stage1g: U[m][q] = sum_n x[m,n] E[n][q] as MFMA GEMM (A=xp entity=m, B=t1 entity=q).
// 4-term split (xH+xL)(cH+cL): product exact at fp32-accum level. Epilogue writes ub
// (stage2's B-operand layout) directly.
__device__ __forceinline__ void s1g_body(
    int gid, const short* __restrict__ xp, const short* __restrict__ t1,
    short* __restrict__ ub) {
  int bc = gid & 63;
  int mt = gid >> 6;                         // 0..7
  int w = threadIdx.x >> 6;                  // qt pair
  int lane = threadIdx.x & 63;
  int quad = lane >> 4, col = lane & 15;
  f32x4 ur[2] = {{0,0,0,0},{0,0,0,0}};
  f32x4 ui[2] = {{0,0,0,0},{0,0,0,0}};
  const short* xb = xp + (size_t)bc * 32768;
#pragma unroll
  for (int ko = 0; ko < 4; ++ko) {
    int noct = ko * 4 + quad;
    const short* pa = xb + ((size_t)(mt * 16 + noct) * 16 + col) * 8;
    bf16x8 xh = *(const bf16x8*)(pa);
    bf16x8 xl = *(const bf16x8*)(pa + 16384);
#pragma unroll
    for (int qq = 0; qq < 2; ++qq) {
      int qt = w * 2 + qq;
      const short* pb = t1 + ((size_t)(qt * 16 + noct) * 16 + col) * 8;
      bf16x8 ch = *(const bf16x8*)(pb);
      bf16x8 cl = *(const bf16x8*)(pb + 16384);
      bf16x8 nh = *(const bf16x8*)(pb + 2 * 16384);
      bf16x8 nl = *(const bf16x8*)(pb + 3 * 16384);
      ur[qq] = MFMA16(xh, ch, ur[qq], 0, 0, 0);
      ur[qq] = MFMA16(xh, cl, ur[qq], 0, 0, 0);
      ur[qq] = MFMA16(xl, ch, ur[qq], 0, 0, 0);
      ur[qq] = MFMA16(xl, cl, ur[qq], 0, 0, 0);
      ui[qq] = MFMA16(xh, nh, ui[qq], 0, 0, 0);
      ui[qq] = MFMA16(xh, nl, ui[qq], 0, 0, 0);
      ui[qq] = MFMA16(xl, nh, ui[qq], 0, 0, 0);
      ui[qq] = MFMA16(xl, nl, ui[qq], 0, 0, 0);
    }
  }
  int moct = mt * 2 + (quad >> 1);
  int j0 = (quad & 1) * 4;
#pragma unroll
  for (int qq = 0; qq < 2; ++qq) {
    int qt = w * 2 + qq;
    unsigned short rh[4], rl[4], ih[4], il[4];
#pragma unroll
    for (int r = 0; r < 4; ++r) {
      rh[r] = bf16h(ur[qq][r]); rl[r] = bf16h(ur[qq][r] - bf16f(rh[r]));
      ih[r] = bf16h(ui[qq][r]); il[r] = bf16h(ui[qq][r] - bf16f(ih[r]));
    }
    size_t base = (size_t)bc * 65536 + (size_t)qt * 2048 + (size_t)moct * 128 +
                  (size_t)col * 8 + j0;
    uint2 o;
    o.x = (unsigned)rh[0] | ((unsigned)rh[1] << 16);
    o.y = (unsigned)rh[2] | ((unsigned)rh[3] << 16);
    *(uint2*)(ub + base) = o;
    o.x = (unsigned)rl[0] | ((unsigned)rl[1] << 16);
    o.y = (unsigned)rl[2] | ((unsigned)rl[3] << 16);
    *(uint2*)(ub + base + 16384) = o;
    o.x = (unsigned)ih[0] | ((unsigned)ih[1] << 16);
    o.y = (unsigned)ih[2] | ((unsigned)ih[3] << 16);
    *(uint2*)(ub + base + 2 * 16384) = o;
    o.x = (unsigned)il[0] | ((unsigned)il[1] << 16);
    o.y = (unsigned)il[2] | ((unsigned)il[3] << 16);
    *(uint2*)(ub + base + 3 * 16384) = o;
  }
}

// stage2: X[p][q] = sum_m T2[p][m] U[m][q]; Z = Keff*X -> zb bf16 splits.
// item = (y<<6)|bcx, y 0..7 pt-pair; wave owns 2 qt, loops pt pair, B-frags reused.
__device__ __forceinline__ void s2_item(
    int item, const short* __restrict__ ub, const short* __restrict__ t2,
    const float2* __restrict__ keff2, short* __restrict__ zb) {
  int bc = remap_bc(item & 63);
  int c = bc & 15;
  int w = threadIdx.x >> 6;
  int lane = threadIdx.x & 63;
  int quad = lane >> 4, col = lane & 15;
  int pt0 = (item >> 6) * 2;                 // pt pair: pt0, pt0+1
  int qh = w;                                // 2 qt per wave
  f32x4 accr[2][2] = {{{0,0,0,0},{0,0,0,0}},{{0,0,0,0},{0,0,0,0}}};
  f32x4 acci[2][2] = {{{0,0,0,0},{0,0,0,0}},{{0,0,0,0},{0,0,0,0}}};
  const short* ubase = ub + (size_t)bc * 65536;
#pragma unroll
  for (int ko = 0; ko < 4; ++ko) {
    int moct = ko * 4 + quad;
    bf16x8 brh[2], brl[2], bih[2], bil[2];
#pragma unroll
    for (int qq = 0; qq < 2; ++qq) {
      int qt = qh * 2 + qq;
      const short* tb = ubase + ((size_t)(qt * 16 + moct) * 16 + col) * 8;
      brh[qq] = *(const bf16x8*)(tb);
      brl[qq] = *(const bf16x8*)(tb + 16384);
      bih[qq] = *(const bf16x8*)(tb + 2 * 16384);
      bil[qq] = *(const bf16x8*)(tb + 3 * 16384);
    }
#pragma unroll
    for (int ptl = 0; ptl < 2; ++ptl) {
      int pt = pt0 + ptl;
      const short* ta = t2 + ((size_t)(pt * 16 + moct) * 16 + col) * 8;
      bf16x8 arh = *(const bf16x8*)(ta);
      bf16x8 arl = *(const bf16x8*)(ta + 32768);
      bf16x8 aih = *(const bf16x8*)(ta + 2 * 32768);
      bf16x8 ail = *(const bf16x8*)(ta + 3 * 32768);
      bf16x8 anh = *(const bf16x8*)(ta + 4 * 32768);
      bf16x8 anl = *(const bf16x8*)(ta + 5 * 32768);
#pragma unroll
      for (int qq = 0; qq < 2; ++qq) {
        accr[ptl][qq] = MFMA16(arh, brh[qq], accr[ptl][qq], 0, 0, 0);
        accr[ptl][qq] = MFMA16(arh, brl[qq], accr[ptl][qq], 0, 0, 0);
        accr[ptl][qq] = MFMA16(arl, brh[qq], accr[ptl][qq], 0, 0, 0);
        accr[ptl][qq] = MFMA16(anh, bih[qq], accr[ptl][qq], 0, 0, 0);
        accr[ptl][qq] = MFMA16(anh, bil[qq], accr[ptl][qq], 0, 0, 0);
        accr[ptl][qq] = MFMA16(anl, bih[qq], accr[ptl][qq], 0, 0, 0);
        acci[ptl][qq] = MFMA16(arh, bih[qq], acci[ptl][qq], 0, 0, 0);
        acci[ptl][qq] = MFMA16(arh, bil[qq], acci[ptl][qq], 0, 0, 0);
        acci[ptl][qq] = MFMA16(arl, bih[qq], acci[ptl][qq], 0, 0, 0);
        acci[ptl][qq] = MFMA16(aih, brh[qq], acci[ptl][qq], 0, 0, 0);
        acci[ptl][qq] = MFMA16(aih, brl[qq], acci[ptl][qq], 0, 0, 0);
        acci[ptl][qq] = MFMA16(ail, brh[qq], acci[ptl][qq], 0, 0, 0);
      }
    }
  }
  size_t joff = (size_t)col * 8 + (quad & 1) * 4;
#pragma unroll
  for (int ptl = 0; ptl < 2; ++ptl) {
    int pt = pt0 + ptl;
    int poct = pt * 2 + (quad >> 1);
#pragma unroll
    for (int qq = 0; qq < 2; ++qq) {
      int qt = qh * 2 + qq;
      int qg = qt * 16 + col;
      float zr[4], zi[4];
#pragma unroll
      for (int r = 0; r < 4; ++r) {
        int pg = pt * 16 + quad * 4 + r;
        int pgc = pg < 255 ? pg : 254;       // keff in-bounds; p=255 slot killed by zero B in t4 k-pad
        float2 k = keff2[((size_t)c * 255 + pgc) * 128 + qg];
        float xr = accr[ptl][qq][r], xi = acci[ptl][qq][r];
        zr[r] = k.x * xr - k.y * xi;
        zi[r] = k.x * xi + k.y * xr;
      }
      unsigned short hr[4], lr[4], hi_[4], li[4];
#pragma unroll
      for (int r = 0; r < 4; ++r) {
        hr[r] = bf16h(zr[r]);  lr[r] = bf16h(zr[r] - bf16f(hr[r]));
        hi_[r] = bf16h(zi[r]); li[r] = bf16h(zi[r] - bf16f(hi_[r]));
      }
      size_t base = (size_t)bc * 131072 + (size_t)qt * 4096 + (size_t)poct * 128 + joff;
      uint2 o;
      o.x = (unsigned)hr[0] | ((unsigned)hr[1] << 16);
      o.y = (unsigned)hr[2] | ((unsigned)hr[3] << 16);
      *(uint2*)(zb + base) = o;
      o.x = (unsigned)lr[0] | ((unsigned)lr[1] << 16);
      o.y = (unsigned)lr[2] | ((unsigned)lr[3] << 16);
      *(uint2*)(zb + base + 32768) = o;
      o.x = (unsigned)hi_[0] | ((unsigned)hi_[1] << 16);
      o.y = (unsigned)hi_[2] | ((unsigned)hi_[3] << 16);
      *(uint2*)(zb + base + 2 * 32768) = o;
      o.x = (unsigned)li[0] | ((unsigned)li[1] << 16);
      o.y = (unsigned)li[2] | ((unsigned)li[3] << 16);
      *(uint2*)(zb + base + 3 * 32768) = o;
    }
  }
}

// stage4 (operands SWAPPED: A=Z -> D rows=q, B=T4 -> D cols=h). item = (y<<6)|bcx, y 0..15.
__device__ __forceinline__ void s4_item(
    int item, const short* __restrict__ zb, const short* __restrict__ t4,
    short* __restrict__ a5, float* __restrict__ v0) {
  int bc = remap_bc(item & 63);
  int w = threadIdx.x >> 6;
  int lane = threadIdx.x & 63;
  int quad = lane >> 4, col = lane & 15;
  int u = (item >> 6) * 4 + w;               // 0..63
  int qt = u >> 3;                           // 0..7 (q-tile -> D rows)
  int kseg = (u >> 2) & 1;                   // p-segment
  int htp = u & 3;                           // 2 h-tiles: htp*2, htp*2+1
  f32x4 accr[2] = {{0,0,0,0},{0,0,0,0}};
  f32x4 acci[2] = {{0,0,0,0},{0,0,0,0}};
  const short* zbase = zb + (size_t)bc * 131072;
#pragma unroll
  for (int ko = 0; ko < 4; ++ko) {
    int poct = kseg * 16 + ko * 4 + quad;
    const short* tz = zbase + ((size_t)(qt * 32 + poct) * 16 + col) * 8;
    bf16x8 zrh = *(const bf16x8*)(tz);
    bf16x8 zrl = *(const bf16x8*)(tz + 32768);
    bf16x8 zih = *(const bf16x8*)(tz + 2 * 32768);
    bf16x8 zil = *(const bf16x8*)(tz + 3 * 32768);
#pragma unroll
    for (int t = 0; t < 2; ++t) {
      int ht = htp * 2 + t;
      const short* ta = t4 + ((size_t)(ht * 32 + poct) * 16 + col) * 8;
      bf16x8 trh = *(const bf16x8*)(ta);
      bf16x8 trl = *(const bf16x8*)(ta + 32768);
      bf16x8 tih = *(const bf16x8*)(ta + 2 * 32768);
      bf16x8 til = *(const bf16x8*)(ta + 3 * 32768);
      bf16x8 tnh = *(const bf16x8*)(ta + 4 * 32768);
      bf16x8 tnl = *(const bf16x8*)(ta + 5 * 32768);
      // Vr = Zr*Tr + Zi*(-Ti)
      accr[t] = MFMA16(zrh, trh, accr[t], 0, 0, 0);
      accr[t] = MFMA16(zrh, trl, accr[t], 0, 0, 0);
      accr[t] = MFMA16(zrl, trh, accr[t], 0, 0, 0);
      accr[t] = MFMA16(zih, tnh, accr[t], 0, 0, 0);
      accr[t] = MFMA16(zih, tnl, accr[t], 0, 0, 0);
      accr[t] = MFMA16(zil, tnh, accr[t], 0, 0, 0);
      // Vi = Zi*Tr + Zr*Ti
      acci[t] = MFMA16(zih, trh, acci[t], 0, 0, 0);
      acci[t] = MFMA16(zih, trl, acci[t], 0, 0, 0);
      acci[t] = MFMA16(zil, trh, acci[t], 0, 0, 0);
      acci[t] = MFMA16(zrh, tih, acci[t], 0, 0, 0);
      acci[t] = MFMA16(zrh, til, acci[t], 0, 0, 0);
      acci[t] = MFMA16(zrl, tih, acci[t], 0, 0, 0);
    }
  }
  // lane rows: q = qt*16 + quad*4 + r  ->  k = kseg*128 + q (contiguous in r)
  int ko_s = kseg * 16 + qt * 2 + (quad >> 1);
  int j0 = (quad & 1) * 4;
#pragma unroll
  for (int t = 0; t < 2; ++t) {
    int ht = htp * 2 + t;
    unsigned short vh[4], vl[4], wh[4], wl2[4];
#pragma unroll
    for (int r = 0; r < 4; ++r) {
      vh[r] = bf16h(accr[t][r]);  vl[r] = bf16h(accr[t][r] - bf16f(vh[r]));
      wh[r] = bf16h(acci[t][r]);  wl2[r] = bf16h(acci[t][r] - bf16f(wh[r]));
    }
    size_t base = (((size_t)(bc * 4) * 8 + ht) * 32 + ko_s) * 128 + (size_t)col * 8 + j0;
    uint2 o;
    o.x = (unsigned)vh[0] | ((unsigned)vh[1] << 16);
    o.y = (unsigned)vh[2] | ((unsigned)vh[3] << 16);
    *(uint2*)(a5 + base) = o;
    o.x = (unsigned)vl[0] | ((unsigned)vl[1] << 16);
    o.y = (unsigned)vl[2] | ((unsigned)vl[3] << 16);
    *(uint2*)(a5 + base + 32768) = o;
    o.x = (unsigned)wh[0] | ((unsigned)wh[1] << 16);
    o.y = (unsigned)wh[2] | ((unsigned)wh[3] << 16);
    *(uint2*)(a5 + base + 2 * 32768) = o;
    o.x = (unsigned)wl2[0] | ((unsigned)wl2[1] << 16);
    o.y = (unsigned)wl2[2] | ((unsigned)wl2[3] << 16);
    *(uint2*)(a5 + base + 3 * 32768) = o;
    if (qt == 0 && quad == 0)                // row 0 => q = 0
      v0[(size_t)(kseg * 64 + bc) * 128 + ht * 16 + col] = accr[t][0];
  }
}

// stage5: O[h][w] = sum_{k=0..255} (Vr*cos + Vi*(-sin)); out = (2O - v0)*1/N^2 + bias.
// item = (y<<6)|bcx, y 0..7.
__device__ __forceinline__ void s5_item(
    int item, const short* __restrict__ a5, const short* __restrict__ t5,
    const float* __restrict__ v0, const float* __restrict__ bias,
    float* __restrict__ out) {
  int bc = remap_bc(item & 63);
  int w = threadIdx.x >> 6;
  int lane = threadIdx.x & 63;
  int quad = lane >> 4, col = lane & 15;
  int u = (item >> 6) * 4 + w;               // 0..31
  int ht = u >> 2;                           // 0..7
  int wtp = u & 3;                           // 2 w-tiles
  f32x4 acc[2] = {{0,0,0,0},{0,0,0,0}};
  const short* abase = a5 + (size_t)bc * 131072;
#pragma unroll
  for (int kc = 0; kc < 8; ++kc) {
    int koq = kc * 4 + quad;                 // k-oct 0..31
    const short* pa = abase + ((size_t)(ht * 32 + koq) * 16 + col) * 8;
    bf16x8 vrh = *(const bf16x8*)(pa);
    bf16x8 vrl = *(const bf16x8*)(pa + 32768);
    bf16x8 vih = *(const bf16x8*)(pa + 2 * 32768);
    bf16x8 vil = *(const bf16x8*)(pa + 3 * 32768);
#pragma unroll
    for (int t = 0; t < 2; ++t) {
      int wt = wtp * 2 + t;
      const short* pb = t5 + ((size_t)(wt * 32 + koq) * 16 + col) * 8;
      bf16x8 tch = *(const bf16x8*)(pb);
      bf16x8 tcl = *(const bf16x8*)(pb + 32768);
      bf16x8 tnh = *(const bf16x8*)(pb + 2 * 32768);
      bf16x8 tnl = *(const bf16x8*)(pb + 3 * 32768);
      acc[t] = MFMA16(vrh, tch, acc[t], 0, 0, 0);
      acc[t] = MFMA16(vrh, tcl, acc[t], 0, 0, 0);
      acc[t] = MFMA16(vrl, tch, acc[t], 0, 0, 0);
      acc[t] = MFMA16(vih, tnh, acc[t], 0, 0, 0);
      acc[t] = MFMA16(vih, tnl, acc[t], 0, 0, 0);
      acc[t] = MFMA16(vil, tnh, acc[t], 0, 0, 0);
    }
  }
  int b = bc >> 4, c = bc & 15;
  float bb = bias[c];
  float v0t[4];
#pragma unroll
  for (int r = 0; r < 4; ++r) {
    int h = ht * 16 + quad * 4 + r;
    v0t[r] = v0[(size_t)bc * 128 + h] + v0[(size_t)(64 + bc) * 128 + h];
  }
#pragma unroll
  for (int t = 0; t < 2; ++t) {
    int ww = (wtp * 2 + t) * 16 + col;
#pragma unroll
    for (int r = 0; r < 4; ++r) {
      int h = ht * 16 + quad * 4 + r;
      out[((size_t)(b * 128 + h) * 128 + ww) * 16 + c] =
          (2.0f * acc[t][r] - v0t[r]) * INV_N2 + bb;
    }
  }
}

// ---------- persistent back-end: A=mid, B=stage2, C=stage4, D=stage5 ----------
// Normal launch; co-residency of all 512 blocks guaranteed by __launch_bounds__(256,2)
// (2 blocks/CU x 256 CU, no LDS). Manual agent-scope grid barrier between phases.
// NO __restrict__ at this level: workspace overlays alias across phases (Sr/Si<->zb,
// xp/t1<->a5); phase bodies carry function-scope restrict.
__global__ __launch_bounds__(256, 2) void backend(
    const float* Sr, const float* Si, float2* keff2,
    const short* xp, const short* t1, short* ub,
    const short* t2, short* zb,
    const short* t4, short* a5, float* v0,
    const short* t5, const float* bias, float* out,
    unsigned* bar, unsigned* gen) {
  int blk = blockIdx.x;                      // 0..511
  // Phase A: mid (2560 items: stripe of 5 -> 4 fold : 1 stage1g)
  for (int it = blk; it < 2560; it += 512) {
    int d = it / 5, r = it - d * 5;
    if (r == 4) {
      s1g_body(d, xp, t1, ub);
    } else {
      int fid = d * 4 + r;
      if (fid < 2040) fold_body(fid, Sr, Si, keff2);
    }
  }
  grid_barrier(bar, gen);
  // Phase B: stage2 (512 items)
  s2_item(blk, ub, t2, keff2, zb);
  grid_barrier(bar, gen);
  // Phase C: stage4 (1024 items)
  for (int it = blk; it < 1024; it += 512) s4_item(it, zb, t4, a5, v0);
  grid_barrier(bar, gen);
  // Phase D: stage5 (512 items)
  s5_item(blk, a5, t5, v0, bias, out);
}

extern "C" void kernel_launch(void* const* d_in, const int* in_sizes, int n_in,
                              void* d_out, int out_size, void* d_ws, size_t ws_size,
                              hipStream_t stream) {
  const float* x  = (const float*)d_in[0];
  const float* kr = (const float*)d_in[1];
  const float* ki = (const float*)d_in[2];
  const float* bs = (const float*)d_in[3];
  float* out = (float*)d_out;

  char* p = (char*)d_ws;
  float2* keff2 = (float2*)p; p += (size_t)16 * 255 * 128 * 8;    // 4.18 MB
  short*  zb    = (short*)p;  p += (size_t)64 * 131072 * 2;       // 16.78 MB
  char*   a5reg = p;
  short*  a5    = (short*)p;  p += (size_t)64 * 131072 * 2;       // 16.78 MB
  short*  ub    = (short*)p;  p += (size_t)64 * 65536 * 2;        // 8.39 MB
  short*  t2    = (short*)p;  p += (size_t)196608 * 2;            // 0.39 MB
  short*  t4    = (short*)p;  p += (size_t)196608 * 2;            // 0.39 MB
  short*  t5    = (short*)p;  p += (size_t)131072 * 2;            // 0.26 MB
  float*  v0    = (float*)p;  p += (size_t)2 * 64 * 128 * 4;      // 64 KB
  unsigned* barws = (unsigned*)p; p += 256;                        // barrier words
  // Sr/Si (8.33 MB) overlay zb (dead after phase A's fold; zb written in phase B).
  float* Sr = (float*)zb;
  float* Si = Sr + 255 * 255 * 16;
  // xp (4.19 MB) and t1 (128 KB) overlay the a5 region, first written in phase C
  // (after phases A/B consumed xp/t1). xp at +0; t1 at +6 MB (in the gap).
  short* xp = (short*)a5reg;
  short* t1 = (short*)(a5reg + 6 * 1024 * 1024);

  hipMemsetAsync(barws, 0, 2 * sizeof(unsigned), stream);
  fused_front<<<11264, 256, 0, stream>>>(kr, ki, Sr, Si, x, xp, t1, t2, t4, t5);
  backend<<<NBLK, 256, 0, stream>>>(Sr, Si, keff2, xp, t1, ub, t2, zb,
                                    t4, a5, v0, t5, bs, out, barws, barws + 1);
}

// Round 9
// 203.784 us; speedup vs baseline: 2.1089x; 2.1089x over previous
//
#include <hip/hip_runtime.h>
#include <math.h>

// FourierConv via DFT-as-GEMM on the MATRIX pipe.
// out[b,h,w,c] = Re(ifft2(fft2(x,255^2)*Ksum))[h+63,w+63] + bias; Ksum = sum_cout K.
// Half-spectrum q=0..127. Stages 1 (n->q), 2 (m->p), 4 (p->h), 5 (q->w real part) are
// bf16 MFMA GEMMs with SPLIT precision (rel err ~2^-17).
// Operand-fragment rule (verified): both MFMA operands use layout [entity=lane&15][k=quad*8+j];
// first arg's entity -> D row (quad*4+reg), second arg's entity -> D col (lane&15).
// stage4 computes D[q][h] (A=Z, B=T4); stage1g emits U directly in stage2's B-operand
// layout (ub). stage5 is a K=256 GEMM + epilogue.
//
// R7 lesson (persistent backend, correct but 280us, all pipes idle): back-end is
// LATENCY-bound (~91MB traffic = ~31us floor, runs ~150us); launch gaps are small; the
// fused-phase occupancy cap (2 blk/CU) made it worse. R8: revert to 5-kernel chain and
// cut one global round-trip instead -- stage4+stage5 merged per (bc,ht): V tiles built in
// a 32KB LDS buffer (exact a5-slice layout), __syncthreads, stage5 reads A-operands from
// LDS (~30cyc) instead of L3 (~500cyc). Removes a5 (34MB) + v0 round-trips + one launch.
// zb re-reads are XCD-local (writer/reader both on XCD bcx%8). MFMA order per acc
// unchanged -> bit-identical output.

constexpr float PI2_OVER_N = 6.28318530717958647692f / 255.0f;
constexpr float INV_N2 = 1.0f / (255.0f * 255.0f);

typedef __attribute__((ext_vector_type(8))) short bf16x8;   // 8 bf16 = 4 VGPR
typedef __attribute__((ext_vector_type(4))) float f32x4;    // MFMA acc / native float4
#define MFMA16 __builtin_amdgcn_mfma_f32_16x16x32_bf16

__device__ __forceinline__ int remap_bc(int xidx) {
  int k = xidx & 7, j = xidx >> 3;
  return ((k >> 1) * 16) + ((k & 1) * 8) + j;   // b = k>>1, c = (k&1)*8 + j
}

__device__ __forceinline__ unsigned short bf16h(float f) {
  unsigned u = __float_as_uint(f);
  return (unsigned short)((u + 0x7FFFu + ((u >> 16) & 1u)) >> 16);
}
__device__ __forceinline__ float bf16f(unsigned short h) {
  return __uint_as_float(((unsigned)h) << 16);
}

// ---------- front bodies ----------

__device__ __forceinline__ void ksum_body(
    int buf, int xb, const float* __restrict__ kr, const float* __restrict__ ki,
    float* __restrict__ Sr, float* __restrict__ Si) {
  const int nrows = 255 * 255 * 16;
  int r = xb * 256 + threadIdx.x;
  if (r >= nrows) return;
  const float* src = (buf == 0) ? kr : ki;
  float* dst = (buf == 0) ? Sr : Si;
  const float4* k4 = (const float4*)(src + (size_t)r * 16);
  float4 a = k4[0], b = k4[1], c = k4[2], d = k4[3];
  dst[r] = a.x + a.y + a.z + a.w + b.x + b.y + b.z + b.w +
           c.x + c.y + c.z + c.w + d.x + d.y + d.z + d.w;
}

// pack_x: xp[bc][plane2: H,L][((mt*16+noct)*16+mcol)*8+j] = split(x[b, m, n, c]),
// m = mt*16+mcol, n = noct*8+j. This is stage1g's A-operand layout (entity=m, k=n).
__device__ __forceinline__ void packx_body(
    int pid, const float* __restrict__ x, short* __restrict__ xp) {
  int bc = pid & 63;                         // b*16 + c
  int mt = pid >> 6;                         // 0..7
  int b = bc >> 4, c = bc & 15;
  int mcol = threadIdx.x & 15;
  int noct = threadIdx.x >> 4;               // 0..15
  int m = mt * 16 + mcol;
  const float* xs = x + ((size_t)(b * 128 + m) * 128 + noct * 8) * 16 + c;
  unsigned short hi[8], lo[8];
#pragma unroll
  for (int j = 0; j < 8; ++j) {
    float v = xs[j * 16];
    hi[j] = bf16h(v);
    lo[j] = bf16h(v - bf16f(hi[j]));
  }
  size_t base = (size_t)bc * 32768 + ((size_t)(mt * 16 + noct) * 16 + mcol) * 8;
  uint4 o;
  o.x = (unsigned)hi[0] | ((unsigned)hi[1] << 16);
  o.y = (unsigned)hi[2] | ((unsigned)hi[3] << 16);
  o.z = (unsigned)hi[4] | ((unsigned)hi[5] << 16);
  o.w = (unsigned)hi[6] | ((unsigned)hi[7] << 16);
  *(uint4*)(xp + base) = o;
  o.x = (unsigned)lo[0] | ((unsigned)lo[1] << 16);
  o.y = (unsigned)lo[2] | ((unsigned)lo[3] << 16);
  o.z = (unsigned)lo[4] | ((unsigned)lo[5] << 16);
  o.w = (unsigned)lo[6] | ((unsigned)lo[7] << 16);
  *(uint4*)(xp + base + 16384) = o;
}

// t1[plane4: cosH,cosL,(-sin)H,(-sin)L][qt8][noct16][qcol16][j8]: E[q][n] = e^{-i th q n}
__device__ __forceinline__ void buildt1_body(int cid, short* __restrict__ t1) {
  int i = cid * 256 + threadIdx.x;           // < 65536
  int plane = i >> 14;
  int r = i & 16383;
  int qt = r >> 11, noct = (r >> 7) & 15, qcol = (r >> 3) & 15, j = r & 7;
  int q = qt * 16 + qcol, n = noct * 8 + j;
  float s, c;
  sincosf(PI2_OVER_N * (float)((q * n) % 255), &s, &c);
  float src = (plane < 2) ? c : -s;
  unsigned short hh = bf16h(src);
  t1[i] = (short)((plane & 1) ? bf16h(src - bf16f(hh)) : hh);
}

// t2[plane6][pt16][moct16][p16][j8]: T2[p][m]=e^{-i th p m}; planes cosH,cosL,TiH,TiL,-TiH,-TiL
// t4[plane6][ht8][poct32][h16][j8]:  T4[h][p]=e^{+i th (h+63)p}; p=255 slot zeroed (K-pad)
// t5[plane4][wt8][koct32][w16][j8]:  T5[w][k]: q=k&127; planes cosH,cosL,(-sin)H,(-sin)L
__device__ __forceinline__ void buildt24_body(
    int cid2, short* __restrict__ t2, short* __restrict__ t4, short* __restrict__ t5) {
  int i = cid2 * 256 + threadIdx.x;          // < 524288
  float s, c;
  if (i < 196608) {
    int plane = i >> 15;
    int r = i & 32767;
    int pt = r >> 11, r2 = r & 2047;
    int moct = r2 >> 7, p = (r2 >> 3) & 15, j = r2 & 7;
    int pg = pt * 16 + p, m = moct * 8 + j;
    int k = ((pg % 255) * m) % 255;
    sincosf(PI2_OVER_N * (float)k, &s, &c);
    float ti = -s;
    float src = (plane < 2) ? c : ((plane < 4) ? ti : -ti);
    unsigned short h = bf16h(src);
    t2[i] = (short)((plane & 1) ? bf16h(src - bf16f(h)) : h);
  } else if (i < 393216) {
    int i2 = i - 196608;
    int plane = i2 >> 15;
    int r = i2 & 32767;
    int ht = r >> 12, r2 = r & 4095;
    int poct = r2 >> 7, h = (r2 >> 3) & 15, j = r2 & 7;
    int p = poct * 8 + j;
    unsigned short val = 0;
    if (p < 255) {
      int hg = ht * 16 + h;
      int k = ((hg + 63) * p) % 255;
      sincosf(PI2_OVER_N * (float)k, &s, &c);
      float src = (plane < 2) ? c : ((plane < 4) ? s : -s);
      unsigned short hh = bf16h(src);
      val = (plane & 1) ? bf16h(src - bf16f(hh)) : hh;
    }
    t4[i2] = (short)val;
  } else {
    int i3 = i - 393216;
    int plane = i3 >> 15;                    // 0..3
    int r = i3 & 32767;
    int wt = r >> 12, r2 = r & 4095;
    int ko = r2 >> 7, wl = (r2 >> 3) & 15, j = r2 & 7;
    int q = (ko * 8 + j) & 127;              // k -> q (both segs identical)
    int ww = wt * 16 + wl;
    sincosf(PI2_OVER_N * (float)(((ww + 63) * q) % 255), &s, &c);
    float src = (plane < 2) ? c : -s;
    unsigned short hh = bf16h(src);
    t5[i3] = (short)((plane & 1) ? bf16h(src - bf16f(hh)) : hh);
  }
}

// fused front: stripe of 4 -> 3 ksum blocks : 1 compute block (pack_x / t1 / t24)
__global__ __launch_bounds__(256) void fused_front(
    const float* __restrict__ kr, const float* __restrict__ ki,
    float* __restrict__ Sr, float* __restrict__ Si,
    const float* __restrict__ x, short* __restrict__ xp,
    short* __restrict__ t1, short* __restrict__ t2,
    short* __restrict__ t4, short* __restrict__ t5) {
  int bid = blockIdx.x;                      // 0..11263
  int d = bid >> 2, r = bid & 3;             // d 0..2815
  if (r == 3) {
    if (d < 512)      packx_body(d, x, xp);
    else if (d < 768) buildt1_body(d - 512, t1);
    else              buildt24_body(d - 768, t2, t4, t5);
  } else {
    int kid = d * 3 + r;
    if (kid < 8192) ksum_body(kid & 1, kid >> 1, kr, ki, Sr, Si);
  }
}

// ---------- mid: fold + stage1g (independent, co-scheduled) ----------

__device__ __forceinline__ void fold_body(
    int fid, const float* __restrict__ Sr, const float* __restrict__ Si,
    float2* __restrict__ keff2) {
  int p = fid % 255;
  int qy = fid / 255;                        // 0..7
  int q = qy * 16 + (threadIdx.x >> 4);
  int c = threadIdx.x & 15;
  int pp = (255 - p) % 255;
  int qq = (255 - q) % 255;
  size_t i0 = (size_t)(p * 255 + q) * 16 + c;
  size_t i1 = (size_t)(pp * 255 + qq) * 16 + c;
  float sr0 = Sr[i0], si0 = Si[i0], sr1 = Sr[i1], si1 = Si[i1];
  float2 v;
  v.x = 0.5f * (sr0 + sr1);
  v.y = 0.5f * (si0 - si1);
  keff2[((size_t)c * 255 + p) * 128 + q] = v;
}

// stage1g: U[m][q] = sum_n x[m,n] E[n][q] as MFMA GEMM (A=xp entity=m, B=t1 entity=q).
// 4-term split (xH+xL)(cH+cL): product exact at fp32-accum level. Epilogue writes ub
// (stage2's B-operand layout) directly.
__device__ __forceinline__ void s1g_body(
    int gid, const short* __restrict__ xp, const short* __restrict__ t1,
    short* __restrict__ ub) {
  int bc = gid & 63;
  int mt = gid >> 6;                         // 0..7
  int w = threadIdx.x >> 6;                  // qt pair
  int lane = threadIdx.x & 63;
  int quad = lane >> 4, col = lane & 15;
  f32x4 ur[2] = {{0,0,0,0},{0,0,0,0}};
  f32x4 ui[2] = {{0,0,0,0},{0,0,0,0}};
  const short* xb = xp + (size_t)bc * 32768;
#pragma unroll
  for (int ko = 0; ko < 4; ++ko) {
    int noct = ko * 4 + quad;
    const short* pa = xb + ((size_t)(mt * 16 + noct) * 16 + col) * 8;
    bf16x8 xh = *(const bf16x8*)(pa);
    bf16x8 xl = *(const bf16x8*)(pa + 16384);
#pragma unroll
    for (int qq = 0; qq < 2; ++qq) {
      int qt = w * 2 + qq;
      const short* pb = t1 + ((size_t)(qt * 16 + noct) * 16 + col) * 8;
      bf16x8 ch = *(const bf16x8*)(pb);
      bf16x8 cl = *(const bf16x8*)(pb + 16384);
      bf16x8 nh = *(const bf16x8*)(pb + 2 * 16384);
      bf16x8 nl = *(const bf16x8*)(pb + 3 * 16384);
      ur[qq] = MFMA16(xh, ch, ur[qq], 0, 0, 0);
      ur[qq] = MFMA16(xh, cl, ur[qq], 0, 0, 0);
      ur[qq] = MFMA16(xl, ch, ur[qq], 0, 0, 0);
      ur[qq] = MFMA16(xl, cl, ur[qq], 0, 0, 0);
      ui[qq] = MFMA16(xh, nh, ui[qq], 0, 0, 0);
      ui[qq] = MFMA16(xh, nl, ui[qq], 0, 0, 0);
      ui[qq] = MFMA16(xl, nh, ui[qq], 0, 0, 0);
      ui[qq] = MFMA16(xl, nl, ui[qq], 0, 0, 0);
    }
  }
  int moct = mt * 2 + (quad >> 1);
  int j0 = (quad & 1) * 4;
#pragma unroll
  for (int qq = 0; qq < 2; ++qq) {
    int qt = w * 2 + qq;
    unsigned short rh[4], rl[4], ih[4], il[4];
#pragma unroll
    for (int r = 0; r < 4; ++r) {
      rh[r] = bf16h(ur[qq][r]); rl[r] = bf16h(ur[qq][r] - bf16f(rh[r]));
      ih[r] = bf16h(ui[qq][r]); il[r] = bf16h(ui[qq][r] - bf16f(ih[r]));
    }
    size_t base = (size_t)bc * 65536 + (size_t)qt * 2048 + (size_t)moct * 128 +
                  (size_t)col * 8 + j0;
    uint2 o;
    o.x = (unsigned)rh[0] | ((unsigned)rh[1] << 16);
    o.y = (unsigned)rh[2] | ((unsigned)rh[3] << 16);
    *(uint2*)(ub + base) = o;
    o.x = (unsigned)rl[0] | ((unsigned)rl[1] << 16);
    o.y = (unsigned)rl[2] | ((unsigned)rl[3] << 16);
    *(uint2*)(ub + base + 16384) = o;
    o.x = (unsigned)ih[0] | ((unsigned)ih[1] << 16);
    o.y = (unsigned)ih[2] | ((unsigned)ih[3] << 16);
    *(uint2*)(ub + base + 2 * 16384) = o;
    o.x = (unsigned)il[0] | ((unsigned)il[1] << 16);
    o.y = (unsigned)il[2] | ((unsigned)il[3] << 16);
    *(uint2*)(ub + base + 3 * 16384) = o;
  }
}

// stripe of 5: 4 fold blocks : 1 stage1g block
__global__ __launch_bounds__(256) void mid(
    const float* __restrict__ Sr, const float* __restrict__ Si,
    float2* __restrict__ keff2,
    const short* __restrict__ xp, const short* __restrict__ t1,
    short* __restrict__ ub) {
  int bid = blockIdx.x;                      // 0..2559
  int d = bid / 5, r = bid - d * 5;
  if (r == 4) {
    s1g_body(d, xp, t1, ub);                 // d 0..511
  } else {
    int fid = d * 4 + r;
    if (fid < 2040) fold_body(fid, Sr, Si, keff2);
  }
}

// ---------- stage2_mfma: X[p][q] = sum_m T2[p][m] U[m][q]; Z = Keff*X -> zb bf16 splits ----------
// zb[bc][plane4][qt8][poct32][q16][j8] (p in k-position for stage4's A side).
// Grid (64 bc, 8 pt-pairs); wave w owns 2 qt, loops pt pair, B-frags reused.
__global__ __launch_bounds__(256) void stage2_mfma(
    const short* __restrict__ ub, const short* __restrict__ t2,
    const float2* __restrict__ keff2, short* __restrict__ zb) {
  int bc = remap_bc(blockIdx.x);
  int c = bc & 15;
  int w = threadIdx.x >> 6;
  int lane = threadIdx.x & 63;
  int quad = lane >> 4, col = lane & 15;
  int pt0 = blockIdx.y * 2;                  // pt pair: pt0, pt0+1
  int qh = w;                                // 2 qt per wave
  f32x4 accr[2][2] = {{{0,0,0,0},{0,0,0,0}},{{0,0,0,0},{0,0,0,0}}};
  f32x4 acci[2][2] = {{{0,0,0,0},{0,0,0,0}},{{0,0,0,0},{0,0,0,0}}};
  const short* ubase = ub + (size_t)bc * 65536;
#pragma unroll
  for (int ko = 0; ko < 4; ++ko) {
    int moct = ko * 4 + quad;
    bf16x8 brh[2], brl[2], bih[2], bil[2];
#pragma unroll
    for (int qq = 0; qq < 2; ++qq) {
      int qt = qh * 2 + qq;
      const short* tb = ubase + ((size_t)(qt * 16 + moct) * 16 + col) * 8;
      brh[qq] = *(const bf16x8*)(tb);
      brl[qq] = *(const bf16x8*)(tb + 16384);
      bih[qq] = *(const bf16x8*)(tb + 2 * 16384);
      bil[qq] = *(const bf16x8*)(tb + 3 * 16384);
    }
#pragma unroll
    for (int ptl = 0; ptl < 2; ++ptl) {
      int pt = pt0 + ptl;
      const short* ta = t2 + ((size_t)(pt * 16 + moct) * 16 + col) * 8;
      bf16x8 arh = *(const bf16x8*)(ta);
      bf16x8 arl = *(const bf16x8*)(ta + 32768);
      bf16x8 aih = *(const bf16x8*)(ta + 2 * 32768);
      bf16x8 ail = *(const bf16x8*)(ta + 3 * 32768);
      bf16x8 anh = *(const bf16x8*)(ta + 4 * 32768);
      bf16x8 anl = *(const bf16x8*)(ta + 5 * 32768);
#pragma unroll
      for (int qq = 0; qq < 2; ++qq) {
        accr[ptl][qq] = MFMA16(arh, brh[qq], accr[ptl][qq], 0, 0, 0);
        accr[ptl][qq] = MFMA16(arh, brl[qq], accr[ptl][qq], 0, 0, 0);
        accr[ptl][qq] = MFMA16(arl, brh[qq], accr[ptl][qq], 0, 0, 0);
        accr[ptl][qq] = MFMA16(anh, bih[qq], accr[ptl][qq], 0, 0, 0);
        accr[ptl][qq] = MFMA16(anh, bil[qq], accr[ptl][qq], 0, 0, 0);
        accr[ptl][qq] = MFMA16(anl, bih[qq], accr[ptl][qq], 0, 0, 0);
        acci[ptl][qq] = MFMA16(arh, bih[qq], acci[ptl][qq], 0, 0, 0);
        acci[ptl][qq] = MFMA16(arh, bil[qq], acci[ptl][qq], 0, 0, 0);
        acci[ptl][qq] = MFMA16(arl, bih[qq], acci[ptl][qq], 0, 0, 0);
        acci[ptl][qq] = MFMA16(aih, brh[qq], acci[ptl][qq], 0, 0, 0);
        acci[ptl][qq] = MFMA16(aih, brl[qq], acci[ptl][qq], 0, 0, 0);
        acci[ptl][qq] = MFMA16(ail, brh[qq], acci[ptl][qq], 0, 0, 0);
      }
    }
  }
  size_t joff = (size_t)col * 8 + (quad & 1) * 4;
#pragma unroll
  for (int ptl = 0; ptl < 2; ++ptl) {
    int pt = pt0 + ptl;
    int poct = pt * 2 + (quad >> 1);
#pragma unroll
    for (int qq = 0; qq < 2; ++qq) {
      int qt = qh * 2 + qq;
      int qg = qt * 16 + col;
      float zr[4], zi[4];
#pragma unroll
      for (int r = 0; r < 4; ++r) {
        int pg = pt * 16 + quad * 4 + r;
        int pgc = pg < 255 ? pg : 254;       // keff in-bounds; p=255 slot killed by zero B in t4 k-pad
        float2 k = keff2[((size_t)c * 255 + pgc) * 128 + qg];
        float xr = accr[ptl][qq][r], xi = acci[ptl][qq][r];
        zr[r] = k.x * xr - k.y * xi;
        zi[r] = k.x * xi + k.y * xr;
      }
      unsigned short hr[4], lr[4], hi_[4], li[4];
#pragma unroll
      for (int r = 0; r < 4; ++r) {
        hr[r] = bf16h(zr[r]);  lr[r] = bf16h(zr[r] - bf16f(hr[r]));
        hi_[r] = bf16h(zi[r]); li[r] = bf16h(zi[r] - bf16f(hi_[r]));
      }
      size_t base = (size_t)bc * 131072 + (size_t)qt * 4096 + (size_t)poct * 128 + joff;
      uint2 o;
      o.x = (unsigned)hr[0] | ((unsigned)hr[1] << 16);
      o.y = (unsigned)hr[2] | ((unsigned)hr[3] << 16);
      *(uint2*)(zb + base) = o;
      o.x = (unsigned)lr[0] | ((unsigned)lr[1] << 16);
      o.y = (unsigned)lr[2] | ((unsigned)lr[3] << 16);
      *(uint2*)(zb + base + 32768) = o;
      o.x = (unsigned)hi_[0] | ((unsigned)hi_[1] << 16);
      o.y = (unsigned)hi_[2] | ((unsigned)hi_[3] << 16);
      *(uint2*)(zb + base + 2 * 32768) = o;
      o.x = (unsigned)li[0] | ((unsigned)li[1] << 16);
      o.y = (unsigned)li[2] | ((unsigned)li[3] << 16);
      *(uint2*)(zb + base + 3 * 32768) = o;
    }
  }
}

// ---------- stage45: fused stage4+stage5 per (bc, ht), V staged in LDS ----------
// Part 1 (= stage4, A=Z B=T4): wave w computes tasks tt = w*4+i, i<4; tt -> (qt=tt>>1,
// kseg=tt&1); single-ht acc (12 MFMAs/ko, same per-acc order as before -> bit-identical).
// V bf16 splits land in vlds[plane4][koct32][col16*8+j] (exact a5-slice layout, 32KB).
// v0 (q=0 row) lands in vz[kseg][h&15] (LDS, no global round trip).
// Part 2 (= stage5, A=vlds B=T5): wave w owns wtp = w (2 w-tiles), K=256 from LDS.
__global__ __launch_bounds__(256) void stage45(
    const short* __restrict__ zb, const short* __restrict__ t4,
    const short* __restrict__ t5, const float* __restrict__ bias,
    float* __restrict__ out) {
  __shared__ __align__(16) short vlds[4 * 32 * 128];   // 32 KB
  __shared__ float vz[2][16];
  int bc = remap_bc(blockIdx.x);
  int ht = blockIdx.y;                       // 0..7
  int w = threadIdx.x >> 6;
  int lane = threadIdx.x & 63;
  int quad = lane >> 4, col = lane & 15;
  const short* zbase = zb + (size_t)bc * 131072;
  // ---- Part 1: 16 (qt,kseg) V-tiles, 4 per wave ----
#pragma unroll
  for (int i = 0; i < 4; ++i) {
    int tt = w * 4 + i;
    int qt = tt >> 1;                        // 0..7
    int kseg = tt & 1;
    f32x4 accr = {0, 0, 0, 0};
    f32x4 acci = {0, 0, 0, 0};
#pragma unroll
    for (int ko = 0; ko < 4; ++ko) {
      int poct = kseg * 16 + ko * 4 + quad;
      const short* tz = zbase + ((size_t)(qt * 32 + poct) * 16 + col) * 8;
      bf16x8 zrh = *(const bf16x8*)(tz);
      bf16x8 zrl = *(const bf16x8*)(tz + 32768);
      bf16x8 zih = *(const bf16x8*)(tz + 2 * 32768);
      bf16x8 zil = *(const bf16x8*)(tz + 3 * 32768);
      const short* ta = t4 + ((size_t)(ht * 32 + poct) * 16 + col) * 8;
      bf16x8 trh = *(const bf16x8*)(ta);
      bf16x8 trl = *(const bf16x8*)(ta + 32768);
      bf16x8 tih = *(const bf16x8*)(ta + 2 * 32768);
      bf16x8 til = *(const bf16x8*)(ta + 3 * 32768);
      bf16x8 tnh = *(const bf16x8*)(ta + 4 * 32768);
      bf16x8 tnl = *(const bf16x8*)(ta + 5 * 32768);
      // Vr = Zr*Tr + Zi*(-Ti)
      accr = MFMA16(zrh, trh, accr, 0, 0, 0);
      accr = MFMA16(zrh, trl, accr, 0, 0, 0);
      accr = MFMA16(zrl, trh, accr, 0, 0, 0);
      accr = MFMA16(zih, tnh, accr, 0, 0, 0);
      accr = MFMA16(zih, tnl, accr, 0, 0, 0);
      accr = MFMA16(zil, tnh, accr, 0, 0, 0);
      // Vi = Zi*Tr + Zr*Ti
      acci = MFMA16(zih, trh, acci, 0, 0, 0);
      acci = MFMA16(zih, trl, acci, 0, 0, 0);
      acci = MFMA16(zil, trh, acci, 0, 0, 0);
      acci = MFMA16(zrh, tih, acci, 0, 0, 0);
      acci = MFMA16(zrh, til, acci, 0, 0, 0);
      acci = MFMA16(zrl, tih, acci, 0, 0, 0);
    }
    // lane rows: q = qt*16 + quad*4 + r  ->  k = kseg*128 + q
    int ko_s = kseg * 16 + qt * 2 + (quad >> 1);
    int j0 = (quad & 1) * 4;
    unsigned short vh[4], vl[4], wh[4], wl2[4];
#pragma unroll
    for (int r = 0; r < 4; ++r) {
      vh[r] = bf16h(accr[r]);  vl[r] = bf16h(accr[r] - bf16f(vh[r]));
      wh[r] = bf16h(acci[r]);  wl2[r] = bf16h(acci[r] - bf16f(wh[r]));
    }
    short* dst = vlds + (size_t)ko_s * 128 + (size_t)col * 8 + j0;  // plane stride 4096
    uint2 o;
    o.x = (unsigned)vh[0] | ((unsigned)vh[1] << 16);
    o.y = (unsigned)vh[2] | ((unsigned)vh[3] << 16);
    *(uint2*)(dst) = o;
    o.x = (unsigned)vl[0] | ((unsigned)vl[1] << 16);
    o.y = (unsigned)vl[2] | ((unsigned)vl[3] << 16);
    *(uint2*)(dst + 4096) = o;
    o.x = (unsigned)wh[0] | ((unsigned)wh[1] << 16);
    o.y = (unsigned)wh[2] | ((unsigned)wh[3] << 16);
    *(uint2*)(dst + 2 * 4096) = o;
    o.x = (unsigned)wl2[0] | ((unsigned)wl2[1] << 16);
    o.y = (unsigned)wl2[2] | ((unsigned)wl2[3] << 16);
    *(uint2*)(dst + 3 * 4096) = o;
    if (qt == 0 && quad == 0)                // row 0 => q = 0
      vz[kseg][col] = accr[0];
  }
  __syncthreads();
  // ---- Part 2: stage5 from LDS; wave w -> wtp = w ----
  f32x4 acc[2] = {{0,0,0,0},{0,0,0,0}};
#pragma unroll
  for (int kc = 0; kc < 8; ++kc) {
    int koq = kc * 4 + quad;                 // k-oct 0..31
    const short* pa = vlds + (size_t)koq * 128 + (size_t)col * 8;
    bf16x8 vrh = *(const bf16x8*)(pa);
    bf16x8 vrl = *(const bf16x8*)(pa + 4096);
    bf16x8 vih = *(const bf16x8*)(pa + 2 * 4096);
    bf16x8 vil = *(const bf16x8*)(pa + 3 * 4096);
#pragma unroll
    for (int t = 0; t < 2; ++t) {
      int wt = w * 2 + t;
      const short* pb = t5 + ((size_t)(wt * 32 + koq) * 16 + col) * 8;
      bf16x8 tch = *(const bf16x8*)(pb);
      bf16x8 tcl = *(const bf16x8*)(pb + 32768);
      bf16x8 tnh = *(const bf16x8*)(pb + 2 * 32768);
      bf16x8 tnl = *(const bf16x8*)(pb + 3 * 32768);
      acc[t] = MFMA16(vrh, tch, acc[t], 0, 0, 0);
      acc[t] = MFMA16(vrh, tcl, acc[t], 0, 0, 0);
      acc[t] = MFMA16(vrl, tch, acc[t], 0, 0, 0);
      acc[t] = MFMA16(vih, tnh, acc[t], 0, 0, 0);
      acc[t] = MFMA16(vih, tnl, acc[t], 0, 0, 0);
      acc[t] = MFMA16(vil, tnh, acc[t], 0, 0, 0);
    }
  }
  int b = bc >> 4, c = bc & 15;
  float bb = bias[c];
  float v0t[4];
#pragma unroll
  for (int r = 0; r < 4; ++r)
    v0t[r] = vz[0][quad * 4 + r] + vz[1][quad * 4 + r];
#pragma unroll
  for (int t = 0; t < 2; ++t) {
    int ww = (w * 2 + t) * 16 + col;
#pragma unroll
    for (int r = 0; r < 4; ++r) {
      int h = ht * 16 + quad * 4 + r;
      out[((size_t)(b * 128 + h) * 128 + ww) * 16 + c] =
          (2.0f * acc[t][r] - v0t[r]) * INV_N2 + bb;
    }
  }
}

extern "C" void kernel_launch(void* const* d_in, const int* in_sizes, int n_in,
                              void* d_out, int out_size, void* d_ws, size_t ws_size,
                              hipStream_t stream) {
  const float* x  = (const float*)d_in[0];
  const float* kr = (const float*)d_in[1];
  const float* ki = (const float*)d_in[2];
  const float* bs = (const float*)d_in[3];
  float* out = (float*)d_out;

  char* p = (char*)d_ws;
  float2* keff2 = (float2*)p; p += (size_t)16 * 255 * 128 * 8;    // 4.18 MB
  short*  zb    = (short*)p;  p += (size_t)64 * 131072 * 2;       // 16.78 MB
  char*   scr   = p;          p += (size_t)64 * 131072 * 2;       // 16.78 MB (xp/t1 scratch)
  short*  ub    = (short*)p;  p += (size_t)64 * 65536 * 2;        // 8.39 MB
  short*  t2    = (short*)p;  p += (size_t)196608 * 2;            // 0.39 MB
  short*  t4    = (short*)p;  p += (size_t)196608 * 2;            // 0.39 MB
  short*  t5    = (short*)p;  p += (size_t)131072 * 2;            // 0.26 MB
  // Sr/Si (8.33 MB) overlay zb (dead after mid's fold; zb written later by stage2).
  float* Sr = (float*)zb;
  float* Si = Sr + 255 * 255 * 16;
  // xp (4.19 MB) and t1 (128 KB) live in the scratch region (a5 is gone -- V now stays
  // in LDS inside stage45). xp at +0; t1 at +6 MB.
  short* xp = (short*)scr;
  short* t1 = (short*)(scr + 6 * 1024 * 1024);

  fused_front<<<11264, 256, 0, stream>>>(kr, ki, Sr, Si, x, xp, t1, t2, t4, t5);
  mid<<<2560, 256, 0, stream>>>(Sr, Si, keff2, xp, t1, ub);
  stage2_mfma<<<dim3(64, 8), 256, 0, stream>>>(ub, t2, keff2, zb);
  stage45<<<dim3(64, 8), 256, 0, stream>>>(zb, t4, t5, bs, out);
}